// Round 9
// baseline (499.431 us; speedup 1.0000x reference)
//
#include <hip/hip_runtime.h>
#include <hip/hip_bf16.h>

// Problem constants (match reference)
#define NPTS 400000
#define NVOX 100000
#define EPSB 1e-3f
#define NBLK_SCAN 391        // ceil(NVOX/256)
#define VPB 32               // voxels per fused block
#define NBLK_F (NVOX / VPB)  // 3125 exactly

// ws layout (in floats) — ~32 MB
#define OFF_ACC4   0                        // 4*NVOX [cnt,sx,sy,sz]
#define OFF_GRAM   (4*NVOX)                 // 72
#define OFF_STATS  (OFF_GRAM + 72)          // 256
#define OFF_P1     (OFF_STATS + 256)        // 32*128
#define ZERO_FLOATS (OFF_P1 + 4096)         // only this prefix is zeroed (1.6 MB)
#define OFF_VTMP   ZERO_FLOATS              // NVOX
#define OFF_BSUM   (OFF_VTMP + NVOX)        // 512
#define OFF_VOFF   (OFF_BSUM + 512)         // NVOX (scatter cursors)
#define OFF_VSTART (OFF_VOFF + NVOX)        // NVOX+8 (start offsets + sentinel)
#define OFF_ORD    (OFF_VSTART + NVOX + 8)  // NPTS
#define OFF_Y1M    (OFF_ORD + NPTS)         // NVOX*64 (fkey, fully written by k_fused)
#define OFF_W0F    (OFF_Y1M + NVOX*64)      // 640
#define OFF_W1B    (OFF_W0F + 640)          // 4096 floats = 8192 bf16

// stats sub-offsets
#define S_SC0 0
#define S_BI0 64
#define S_SC1 128
#define S_BI1 192

#define XTB_LD 136
#define HT_LD  65
#define GBLK 782

typedef __bf16 bf16x8 __attribute__((ext_vector_type(8)));
typedef float  f32x4  __attribute__((ext_vector_type(4)));

__device__ __forceinline__ float b2f(__hip_bfloat16 h) { return __bfloat162float(h); }
__device__ __forceinline__ float bfbits2f(unsigned short u) {
    return __uint_as_float((unsigned int)u << 16);
}
__device__ __forceinline__ unsigned short bf16u(float f) {
    __hip_bfloat16 h = __float2bfloat16(f);
    return __builtin_bit_cast(unsigned short, h);
}
__device__ __forceinline__ unsigned int fkey(float f) {
    unsigned int u = __float_as_uint(f);
    return (u & 0x80000000u) ? ~u : (u | 0x80000000u);
}
__device__ __forceinline__ float funkey(unsigned int k) {
    unsigned int u = (k & 0x80000000u) ? (k & 0x7FFFFFFFu) : ~k;
    return __uint_as_float(u);
}

__device__ __forceinline__ void compute_x(const __hip_bfloat16* __restrict__ feat,
                                          const float* __restrict__ acc4,
                                          const int* __restrict__ coors,
                                          long i, int v, float* xv) {
    ushort4 f4 = *(const ushort4*)(feat + 4 * i);
    float px = bfbits2f(f4.x), py = bfbits2f(f4.y), pz = bfbits2f(f4.z), it = bfbits2f(f4.w);
    float4 a4 = *(const float4*)&acc4[4 * (long)v];
    float ic = 1.0f / a4.x;
    int4 c4 = *(const int4*)&coors[4 * (long)v];   // (b, z, y, x)
    xv[0] = px; xv[1] = py; xv[2] = pz;
    xv[3] = px - a4.y * ic; xv[4] = py - a4.z * ic; xv[5] = pz - a4.w * ic;
    xv[6] = px - ((float)c4.w * 0.2f + 0.1f);
    xv[7] = py - ((float)c4.z * 0.2f + 0.1f - 40.0f);
    xv[8] = pz - ((float)c4.y * 4.0f + 2.0f - 3.0f);
    xv[9] = it;
}

// ---- K0: W0 -> fp32; W1 -> bf16 MFMA B-fragment order ----
__global__ void k_wconv(const __hip_bfloat16* __restrict__ W0,
                        const __hip_bfloat16* __restrict__ W1,
                        float* __restrict__ W0f, unsigned short* __restrict__ w1b) {
    int t = threadIdx.x;
    for (int j = t; j < 640; j += 256) W0f[j] = b2f(W0[j]);
    for (int f = t; f < 8192; f += 256) {
        int j  = f & 7;
        int l  = (f >> 3) & 63;
        int ks = (f >> 9) & 3;
        int ct = f >> 11;
        int ch = ct * 16 + (l & 15);
        int k  = ks * 32 + ((l >> 4) & 3) * 8 + j;
        w1b[f] = __builtin_bit_cast(unsigned short, W1[ch * 128 + k]);
    }
}

// ---- K1: per-voxel count + xyz sums ----
__global__ void k_vsum(const __hip_bfloat16* __restrict__ feat,
                       const int* __restrict__ inv,
                       float* __restrict__ acc4) {
    long t = (long)blockIdx.x * 256 + threadIdx.x;
    int pt = (int)(t >> 2);
    int comp = (int)(t & 3);
    if (pt >= NPTS) return;
    float val = (comp == 0) ? 1.0f : b2f(feat[4 * pt + comp - 1]);
    int v = inv[pt];
    atomicAdd(&acc4[(long)v * 4 + comp], val);
}

// ---- prefix scan of voxel counts ----
__global__ void k_scan1(const float* __restrict__ acc4,
                        int* __restrict__ vtmp, int* __restrict__ bsum) {
    __shared__ int sc[256];
    int b = blockIdx.x, t = threadIdx.x;
    int v = b * 256 + t;
    int c = (v < NVOX) ? (int)acc4[4 * (long)v] : 0;
    sc[t] = c;
    __syncthreads();
    int val = c;
    for (int off = 1; off < 256; off <<= 1) {
        int x = (t >= off) ? sc[t - off] : 0;
        __syncthreads();
        val += x; sc[t] = val;
        __syncthreads();
    }
    if (v < NVOX) vtmp[v] = val - c;
    if (t == 255) bsum[b] = val;
}

__global__ void k_scan2(int* __restrict__ bsum) {
    __shared__ int sc[512];
    int t = threadIdx.x;
    int c = (t < NBLK_SCAN) ? bsum[t] : 0;
    sc[t] = c;
    __syncthreads();
    int val = c;
    for (int off = 1; off < 512; off <<= 1) {
        int x = (t >= off) ? sc[t - off] : 0;
        __syncthreads();
        val += x; sc[t] = val;
        __syncthreads();
    }
    if (t < NBLK_SCAN) bsum[t] = val - c;
}

__global__ void k_scan3(const int* __restrict__ vtmp, const int* __restrict__ bsum,
                        int* __restrict__ voff, int* __restrict__ vstart) {
    int v = blockIdx.x * 256 + threadIdx.x;
    if (v < NVOX) {
        int s = vtmp[v] + bsum[v >> 8];
        voff[v] = s;
        vstart[v] = s;
    }
    if (v == 0) vstart[NVOX] = NPTS;
}

// ---- K2: fused Gram stats + counting-sort scatter (ord only) ----
__global__ __launch_bounds__(256, 4)
void k_prep(const __hip_bfloat16* __restrict__ feat,
            const int* __restrict__ inv,
            const int* __restrict__ coors,
            const float* __restrict__ acc4,
            int* __restrict__ voff,
            int* __restrict__ ord,
            float* __restrict__ gram) {
    __shared__ float gs[72];
    int t = threadIdx.x;
    if (t < 72) gs[t] = 0.0f;
    __syncthreads();

    float sx[10], sxx[55];
#pragma unroll
    for (int a = 0; a < 10; a++) sx[a] = 0.0f;
#pragma unroll
    for (int a = 0; a < 55; a++) sxx[a] = 0.0f;

    for (long i = (long)blockIdx.x * 256 + t; i < NPTS; i += (long)GBLK * 256) {
        int v = inv[i];
        float xv[10];
        compute_x(feat, acc4, coors, i, v, xv);
        int idx = 0;
#pragma unroll
        for (int a = 0; a < 10; a++) {
            sx[a] += xv[a];
#pragma unroll
            for (int b = 0; b <= a; b++) sxx[idx++] += xv[a] * xv[b];
        }
        int pos = atomicAdd(&voff[v], 1);
        ord[pos] = (int)i;
    }

#pragma unroll
    for (int v = 0; v < 65; v++) {
        float s = (v < 10) ? sx[v] : sxx[v - 10];
        for (int m = 32; m >= 1; m >>= 1) s += __shfl_xor(s, m);
        if ((t & 63) == 0) atomicAdd(&gs[v], s);
    }
    __syncthreads();
    if (t < 65) atomicAdd(&gram[t], gs[t]);
}

// ---- finalize layer-0 BN from Gram ----
__global__ void k_finalize0(const float* __restrict__ gram,
                            const float* __restrict__ W0f,
                            const __hip_bfloat16* __restrict__ gamma,
                            const __hip_bfloat16* __restrict__ beta,
                            float* __restrict__ stats) {
    int c = threadIdx.x;
    if (c >= 64) return;
    float w[10];
#pragma unroll
    for (int k = 0; k < 10; k++) w[k] = W0f[c*10 + k];
    float sum = 0.0f, sq = 0.0f;
#pragma unroll
    for (int a = 0; a < 10; a++) {
        sum += w[a] * gram[a];
        float ta = 0.0f;
#pragma unroll
        for (int b = 0; b < 10; b++) {
            int hi = (a >= b) ? a : b, lo = (a >= b) ? b : a;
            ta += w[b] * gram[10 + hi*(hi+1)/2 + lo];
        }
        sq += w[a] * ta;
    }
    float mu  = sum * (1.0f / NPTS);
    float var = sq * (1.0f / NPTS) - mu * mu;
    float g   = b2f(gamma[c]) * rsqrtf(var + EPSB);
    stats[S_SC0 + c] = g;
    stats[S_BI0 + c] = b2f(beta[c]) - mu * g;
}

// ---- finalize layer-1 BN ----
__global__ void k_finalize1(const float* __restrict__ P1,
                            const __hip_bfloat16* __restrict__ gamma,
                            const __hip_bfloat16* __restrict__ beta,
                            float* __restrict__ stats) {
    int c = threadIdx.x;
    if (c >= 64) return;
    float sum = 0.0f, sq = 0.0f;
    for (int s = 0; s < 32; s++) {
        sum += P1[s*128 + c];
        sq  += P1[s*128 + 64 + c];
    }
    float mu  = sum * (1.0f / NPTS);
    float var = sq * (1.0f / NPTS) - mu * mu;
    float g   = b2f(gamma[c]) * rsqrtf(var + EPSB);
    stats[S_SC1 + c] = g;
    stats[S_BI1 + c] = b2f(beta[c]) - mu * g;
}

// ---- K3: FUSED layer0-max + layer1 MFMA per 32-voxel block.
// Block owns all points of voxels [vb, vb+VPB) (sorted-contiguous), so v0 and
// the y1 segment-max live entirely in LDS; y1m rows written once, NO atomics.
__global__ __launch_bounds__(256, 4)
void k_fused(const int* __restrict__ ord,
             const int* __restrict__ vstart,
             const __hip_bfloat16* __restrict__ feat,
             const float* __restrict__ acc4, const int* __restrict__ coors,
             const float* __restrict__ W0f,
             const unsigned short* __restrict__ w1b,
             const float* __restrict__ stats,
             float* __restrict__ P1,
             unsigned int* __restrict__ y1m) {
    __shared__ union {
        unsigned short xtb[64 * XTB_LD];   // phase B staging (17408 B)
        float ht[64 * HT_LD];              // phase A transpose (16640 B)
    } sm;
    __shared__ unsigned int vmax[VPB * 64];     // h0 max (plain bits, h0>=0)
    __shared__ unsigned int y1v[VPB * 64];      // y1 max (fkey)
    __shared__ unsigned short vmaxb[VPB * 64];  // v0 rows as bf16
    __shared__ int starts[VPB + 1];
    __shared__ int lvoxs[64];

    int t = threadIdx.x, w = t >> 6, l = t & 63;
    int quad = l >> 4, lm = l & 15;
    int vb = blockIdx.x * VPB;

    for (int j = t; j < VPB * 64; j += 256) { vmax[j] = 0u; y1v[j] = 0u; }
    if (t <= VPB) starts[t] = vstart[vb + t];
    __syncthreads();
    int pbase = starts[0];
    int np = starts[VPB] - pbase;
    int nch = (np + 63) >> 6;

    bf16x8 bfrag[4];
    const uint4* wf = (const uint4*)w1b;
#pragma unroll
    for (int ks = 0; ks < 4; ks++)
        bfrag[ks] = __builtin_bit_cast(bf16x8, wf[(w * 4 + ks) * 64 + l]);

    // ================= PHASE A: h0 + per-voxel max in LDS =================
    for (int c = 0; c < nch; c++) {
        int q = c * 64 + l;
        bool val = q < np;
        int lv = 0;
        float xv[10];
#pragma unroll
        for (int k = 0; k < 10; k++) xv[k] = 0.0f;
        if (val) {
            int pg = pbase + q;
            int lo = 0, hi = VPB;
            while (hi - lo > 1) { int mid = (lo + hi) >> 1; if (starts[mid] <= pg) lo = mid; else hi = mid; }
            lv = lo;
            int i = ord[pg];
            compute_x(feat, acc4, coors, (long)i, vb + lv, xv);
        }
        if (w == 0) lvoxs[l] = val ? lv : -1;
        int cw = w * 16;
#pragma unroll
        for (int j = 0; j < 16; j++) {
            int ch = cw + j;
            float y = 0.0f;
#pragma unroll
            for (int k = 0; k < 10; k++) y += xv[k] * W0f[ch*10 + k];
            float h = fmaxf(stats[S_SC0 + ch] * y + stats[S_BI0 + ch], 0.0f);
            sm.ht[l * HT_LD + ch] = val ? h : 0.0f;
        }
        __syncthreads();
        // lane = channel; walk 16 sorted points, run-combined LDS atomicMax
        unsigned int mk = 0u;
#pragma unroll
        for (int j = 0; j < 16; j++) {
            int p = w * 16 + j;
            int lv2 = lvoxs[p];
            if (lv2 >= 0) {
                unsigned int hb = __float_as_uint(sm.ht[p * HT_LD + l]);
                mk = (hb > mk) ? hb : mk;
                if (j == 15 || lvoxs[p + 1] != lv2) {
                    atomicMax(&vmax[lv2 * 64 + l], mk);
                    mk = 0u;
                }
            }
        }
        __syncthreads();
    }
    // v0 rows -> bf16 once
    for (int j = t; j < VPB * 64; j += 256)
        vmaxb[j] = bf16u(__uint_as_float(vmax[j]));
    __syncthreads();

    // ================= PHASE B: MFMA + stats + y1 max in LDS =================
    float ssum = 0.0f, ssq = 0.0f;
    for (int c = 0; c < nch; c++) {
        int q = c * 64 + l;
        bool val = q < np;
        int lv = 0;
        float xv[10];
#pragma unroll
        for (int k = 0; k < 10; k++) xv[k] = 0.0f;
        if (val) {
            int pg = pbase + q;
            int lo = 0, hi = VPB;
            while (hi - lo > 1) { int mid = (lo + hi) >> 1; if (starts[mid] <= pg) lo = mid; else hi = mid; }
            lv = lo;
            int i = ord[pg];
            compute_x(feat, acc4, coors, (long)i, vb + lv, xv);
        }
        if (w == 0) lvoxs[l] = val ? lv : -1;
        int cw = w * 16;
#pragma unroll
        for (int jj = 0; jj < 8; jj++) {
            int c0 = cw + 2 * jj, c1 = c0 + 1;
            float ya = 0.0f, yb = 0.0f;
#pragma unroll
            for (int k = 0; k < 10; k++) {
                ya += xv[k] * W0f[c0*10 + k];
                yb += xv[k] * W0f[c1*10 + k];
            }
            float ha = val ? fmaxf(stats[S_SC0 + c0] * ya + stats[S_BI0 + c0], 0.0f) : 0.0f;
            float hb = val ? fmaxf(stats[S_SC0 + c1] * yb + stats[S_BI0 + c1], 0.0f) : 0.0f;
            unsigned int pk = (unsigned int)bf16u(ha) | ((unsigned int)bf16u(hb) << 16);
            *(unsigned int*)&sm.xtb[l * XTB_LD + c0] = pk;
        }
        if (w == 0) {          // v0 half: 128B LDS->LDS copy per point
            uint4* dst = (uint4*)&sm.xtb[l * XTB_LD + 64];
            if (val) {
                const uint4* src = (const uint4*)&vmaxb[lv * 64];
#pragma unroll
                for (int u = 0; u < 4; u++) dst[u] = src[u];
            } else {
                uint4 z = {0u, 0u, 0u, 0u};
#pragma unroll
                for (int u = 0; u < 4; u++) dst[u] = z;
            }
        }
        __syncthreads();

        f32x4 acc[4];
#pragma unroll
        for (int pg = 0; pg < 4; pg++) acc[pg] = (f32x4){0.f, 0.f, 0.f, 0.f};
#pragma unroll
        for (int ks = 0; ks < 4; ks++) {
#pragma unroll
            for (int pg = 0; pg < 4; pg++) {
                const uint4* ap = (const uint4*)&sm.xtb[(pg * 16 + lm) * XTB_LD + ks * 32 + quad * 8];
                bf16x8 a = __builtin_bit_cast(bf16x8, *ap);
                acc[pg] = __builtin_amdgcn_mfma_f32_16x16x32_bf16(a, bfrag[ks], acc[pg], 0, 0, 0);
            }
        }

        // stats + y1 LDS max (C layout: point row = pg*16 + quad*4 + r, ch = w*16+lm)
#pragma unroll
        for (int pg = 0; pg < 4; pg++) {
            unsigned int mk = 0u;
#pragma unroll
            for (int r = 0; r < 4; r++) {
                float y = acc[pg][r];
                ssum += y; ssq += y * y;
                int p = pg * 16 + quad * 4 + r;
                int lv2 = lvoxs[p];
                if (lv2 >= 0) {
                    unsigned int k2 = fkey(y);
                    mk = (k2 > mk) ? k2 : mk;
                    if (r == 3 || lvoxs[p + 1] != lv2) {
                        atomicMax(&y1v[lv2 * 64 + w * 16 + lm], mk);
                        mk = 0u;
                    }
                }
            }
        }
        __syncthreads();
    }

    // write owned y1 rows once — plain coalesced stores, no global atomics
    for (int j = t; j < VPB * 64; j += 256)
        y1m[(long)vb * 64 + j] = y1v[j];

    ssum += __shfl_xor(ssum, 16); ssq += __shfl_xor(ssq, 16);
    ssum += __shfl_xor(ssum, 32); ssq += __shfl_xor(ssq, 32);
    if (l < 16) {
        int slot = blockIdx.x & 31;
        atomicAdd(&P1[slot * 128 + w * 16 + lm], ssum);
        atomicAdd(&P1[slot * 128 + 64 + w * 16 + lm], ssq);
    }
}

// ---- K4: emit output: feats = relu(bn1(decode(y1max))), then bf16-rounded coors ----
__global__ void k_out(const unsigned int* __restrict__ y1m,
                      const float* __restrict__ stats,
                      const int* __restrict__ coors,
                      float* __restrict__ out) {
    long t = (long)blockIdx.x * 256 + threadIdx.x;
    const long nfeat = (long)NVOX * 64;
    if (t < nfeat) {
        int c = (int)(t & 63);
        float y = funkey(y1m[t]);
        out[t] = fmaxf(stats[S_SC1 + c] * y + stats[S_BI1 + c], 0.0f);
    } else if (t < nfeat + (long)NVOX * 4) {
        out[t] = b2f(__float2bfloat16((float)coors[t - nfeat]));
    }
}

extern "C" void kernel_launch(void* const* d_in, const int* in_sizes, int n_in,
                              void* d_out, int out_size, void* d_ws, size_t ws_size,
                              hipStream_t stream) {
    const __hip_bfloat16* feat = (const __hip_bfloat16*)d_in[0];
    const __hip_bfloat16* W0   = (const __hip_bfloat16*)d_in[1];
    const __hip_bfloat16* g0   = (const __hip_bfloat16*)d_in[2];
    const __hip_bfloat16* be0  = (const __hip_bfloat16*)d_in[3];
    const __hip_bfloat16* W1   = (const __hip_bfloat16*)d_in[4];
    const __hip_bfloat16* g1   = (const __hip_bfloat16*)d_in[5];
    const __hip_bfloat16* be1  = (const __hip_bfloat16*)d_in[6];
    const int* inv   = (const int*)d_in[7];
    const int* coors = (const int*)d_in[8];
    float* out = (float*)d_out;

    float* ws    = (float*)d_ws;
    float* acc4  = ws + OFF_ACC4;
    float* gram  = ws + OFF_GRAM;
    float* stats = ws + OFF_STATS;
    float* P1    = ws + OFF_P1;
    int* vtmp    = (int*)(ws + OFF_VTMP);
    int* bsum    = (int*)(ws + OFF_BSUM);
    int* voff    = (int*)(ws + OFF_VOFF);
    int* vstart  = (int*)(ws + OFF_VSTART);
    int* ord     = (int*)(ws + OFF_ORD);
    unsigned int* y1m = (unsigned int*)(ws + OFF_Y1M);
    float* W0f   = ws + OFF_W0F;
    unsigned short* w1b = (unsigned short*)(ws + OFF_W1B);

    hipMemsetAsync(ws, 0, (size_t)ZERO_FLOATS * sizeof(float), stream);

    k_wconv<<<1, 256, 0, stream>>>(W0, W1, W0f, w1b);
    k_vsum<<<(4 * NPTS + 255) / 256, 256, 0, stream>>>(feat, inv, acc4);
    k_scan1<<<NBLK_SCAN, 256, 0, stream>>>(acc4, vtmp, bsum);
    k_scan2<<<1, 512, 0, stream>>>(bsum);
    k_scan3<<<NBLK_SCAN, 256, 0, stream>>>(vtmp, bsum, voff, vstart);
    k_prep<<<GBLK, 256, 0, stream>>>(feat, inv, coors, acc4, voff, ord, gram);
    k_finalize0<<<1, 64, 0, stream>>>(gram, W0f, g0, be0, stats);
    k_fused<<<NBLK_F, 256, 0, stream>>>(ord, vstart, feat, acc4, coors,
                                        W0f, w1b, stats, P1, y1m);
    k_finalize1<<<1, 64, 0, stream>>>(P1, g1, be1, stats);

    const long nout = (long)NVOX * 64 + (long)NVOX * 4;
    k_out<<<(int)((nout + 255) / 256), 256, 0, stream>>>(y1m, stats, coors, out);
}

// Round 10
// 338.851 us; speedup vs baseline: 1.4739x; 1.4739x over previous
//
#include <hip/hip_runtime.h>
#include <hip/hip_bf16.h>

// Problem constants (match reference)
#define NPTS 400000          // == 6250 * 64 exactly
#define NVOX 100000
#define EPSB 1e-3f
#define NTILE 6250
#define NBLK_SCAN 391        // ceil(NVOX/256)

// ws layout (in floats) — ~57 MB (round 2-7 used ~59 MB safely)
#define OFF_ACC4   0                          // 4*NVOX [cnt,sx,sy,sz]
#define OFF_GRAMP  (4*NVOX)                   // 32 slots * 72 (gram partials)
#define OFF_STATS  (OFF_GRAMP + 2304)         // 256: sc0|bi0|sc1|bi1
#define OFF_P1     (OFF_STATS + 256)          // 32 slots * 128
#define OFF_V0R    (OFF_P1 + 4096)            // NVOX*64 (raw y0 max, fkey)
#define OFF_Y1M    (OFF_V0R + NVOX*64)        // NVOX*64 (raw y1 max, fkey)
#define ZERO_FLOATS (OFF_Y1M + NVOX*64)       // zeroed prefix (~53 MB)
#define OFF_VTMP   ZERO_FLOATS                // NVOX
#define OFF_BSUM   (OFF_VTMP + NVOX)          // 512
#define OFF_VOFF   (OFF_BSUM + 512)           // NVOX (scatter cursors)
#define OFF_ORD    (OFF_VOFF + NVOX)          // NPTS
#define OFF_VS     (OFF_ORD + NPTS)           // NPTS (vsorted)
#define OFF_W0F    (OFF_VS + NPTS)            // 640
#define OFF_W1B    (OFF_W0F + 640)            // 4096 floats = 8192 bf16

// stats sub-offsets
#define S_SC0 0
#define S_BI0 64
#define S_SC1 128
#define S_BI1 192

#define XTB_LD 136
#define HT_LD  65

typedef __bf16 bf16x8 __attribute__((ext_vector_type(8)));
typedef float  f32x4  __attribute__((ext_vector_type(4)));

__device__ __forceinline__ float b2f(__hip_bfloat16 h) { return __bfloat162float(h); }
__device__ __forceinline__ float bfbits2f(unsigned short u) {
    return __uint_as_float((unsigned int)u << 16);
}
__device__ __forceinline__ unsigned short bf16u(float f) {
    __hip_bfloat16 h = __float2bfloat16(f);
    return __builtin_bit_cast(unsigned short, h);
}
__device__ __forceinline__ unsigned int fkey(float f) {
    unsigned int u = __float_as_uint(f);
    return (u & 0x80000000u) ? ~u : (u | 0x80000000u);
}
__device__ __forceinline__ float funkey(unsigned int k) {
    unsigned int u = (k & 0x80000000u) ? (k & 0x7FFFFFFFu) : ~k;
    return __uint_as_float(u);
}

__device__ __forceinline__ void compute_x(const __hip_bfloat16* __restrict__ feat,
                                          const float* __restrict__ acc4,
                                          const int* __restrict__ coors,
                                          long i, int v, float* xv) {
    ushort4 f4 = *(const ushort4*)(feat + 4 * i);
    float px = bfbits2f(f4.x), py = bfbits2f(f4.y), pz = bfbits2f(f4.z), it = bfbits2f(f4.w);
    float4 a4 = *(const float4*)&acc4[4 * (long)v];
    float ic = 1.0f / a4.x;
    int4 c4 = *(const int4*)&coors[4 * (long)v];   // (b, z, y, x)
    xv[0] = px; xv[1] = py; xv[2] = pz;
    xv[3] = px - a4.y * ic; xv[4] = py - a4.z * ic; xv[5] = pz - a4.w * ic;
    xv[6] = px - ((float)c4.w * 0.2f + 0.1f);
    xv[7] = py - ((float)c4.z * 0.2f + 0.1f - 40.0f);
    xv[8] = pz - ((float)c4.y * 4.0f + 2.0f - 3.0f);
    xv[9] = it;
}

// ---- K0: W0 -> fp32; W1 -> bf16 MFMA B-fragment order ----
__global__ void k_wconv(const __hip_bfloat16* __restrict__ W0,
                        const __hip_bfloat16* __restrict__ W1,
                        float* __restrict__ W0f, unsigned short* __restrict__ w1b) {
    int t = threadIdx.x;
    for (int j = t; j < 640; j += 256) W0f[j] = b2f(W0[j]);
    for (int f = t; f < 8192; f += 256) {
        int j  = f & 7;
        int l  = (f >> 3) & 63;
        int ks = (f >> 9) & 3;
        int ct = f >> 11;
        int ch = ct * 16 + (l & 15);
        int k  = ks * 32 + ((l >> 4) & 3) * 8 + j;
        w1b[f] = __builtin_bit_cast(unsigned short, W1[ch * 128 + k]);
    }
}

// ---- K1: per-voxel count + xyz sums ----
__global__ void k_vsum(const __hip_bfloat16* __restrict__ feat,
                       const int* __restrict__ inv,
                       float* __restrict__ acc4) {
    long t = (long)blockIdx.x * 256 + threadIdx.x;
    int pt = (int)(t >> 2);
    int comp = (int)(t & 3);
    if (pt >= NPTS) return;
    float val = (comp == 0) ? 1.0f : b2f(feat[4 * pt + comp - 1]);
    int v = inv[pt];
    atomicAdd(&acc4[(long)v * 4 + comp], val);
}

// ---- prefix scan of voxel counts ----
__global__ void k_scan1(const float* __restrict__ acc4,
                        int* __restrict__ vtmp, int* __restrict__ bsum) {
    __shared__ int sc[256];
    int b = blockIdx.x, t = threadIdx.x;
    int v = b * 256 + t;
    int c = (v < NVOX) ? (int)acc4[4 * (long)v] : 0;
    sc[t] = c;
    __syncthreads();
    int val = c;
    for (int off = 1; off < 256; off <<= 1) {
        int x = (t >= off) ? sc[t - off] : 0;
        __syncthreads();
        val += x; sc[t] = val;
        __syncthreads();
    }
    if (v < NVOX) vtmp[v] = val - c;
    if (t == 255) bsum[b] = val;
}

__global__ void k_scan2(int* __restrict__ bsum) {
    __shared__ int sc[512];
    int t = threadIdx.x;
    int c = (t < NBLK_SCAN) ? bsum[t] : 0;
    sc[t] = c;
    __syncthreads();
    int val = c;
    for (int off = 1; off < 512; off <<= 1) {
        int x = (t >= off) ? sc[t - off] : 0;
        __syncthreads();
        val += x; sc[t] = val;
        __syncthreads();
    }
    if (t < NBLK_SCAN) bsum[t] = val - c;
}

__global__ void k_scan3(const int* __restrict__ vtmp, const int* __restrict__ bsum,
                        int* __restrict__ voff) {
    int v = blockIdx.x * 256 + threadIdx.x;
    if (v < NVOX) voff[v] = vtmp[v] + bsum[v >> 8];
}

// ---- K2: counting-sort scatter ONLY (light) ----
__global__ void k_prep(const int* __restrict__ inv,
                       int* __restrict__ voff,
                       int* __restrict__ ord, int* __restrict__ vsorted) {
    int i = blockIdx.x * 256 + threadIdx.x;
    if (i >= NPTS) return;
    int v = inv[i];
    int pos = atomicAdd(&voff[v], 1);
    ord[pos] = i;
    vsorted[pos] = v;
}

// ---- K3: sorted pass: Gram stats + RAW y0 per-voxel max (fkey, no BN dep).
// segment_max(relu(bn0(y0))) == relu(bn0(segment_max(y0))) (monotone affine+relu).
__global__ __launch_bounds__(256, 6)
void k_h0gram(const int* __restrict__ ord, const int* __restrict__ vsorted,
              const __hip_bfloat16* __restrict__ feat,
              const float* __restrict__ acc4, const int* __restrict__ coors,
              const float* __restrict__ W0f,
              float* __restrict__ gramp,
              unsigned int* __restrict__ v0r) {
    __shared__ float ht[64 * HT_LD];
    __shared__ int invs[64];
    int t = threadIdx.x, w = t >> 6, l = t & 63;
    long base = (long)blockIdx.x * 64;
    int i = ord[base + l];
    int v = vsorted[base + l];
    if (w == 0) invs[l] = v;

    float xv[10];
    compute_x(feat, acc4, coors, (long)i, v, xv);

    // Gram: 65 items striped across the 4 waves (each wave sees the same 64 pts)
    {
        int slot = blockIdx.x & 31;
        for (int item = w; item < 65; item += 4) {
            float s;
            if (item < 10) s = xv[item];
            else {
                int idx = item - 10;
                // idx = a*(a+1)/2 + b
                int a = (int)((sqrtf(8.0f * idx + 1.0f) - 1.0f) * 0.5f);
                while ((a + 1) * (a + 2) / 2 <= idx) a++;
                while (a * (a + 1) / 2 > idx) a--;
                int b = idx - a * (a + 1) / 2;
                s = xv[a] * xv[b];
            }
            for (int m = 32; m >= 1; m >>= 1) s += __shfl_xor(s, m);
            if (l == 0) atomicAdd(&gramp[slot * 72 + item], s);
        }
    }

    // raw y0, 16 channels per wave -> LDS transpose
    int cw = w * 16;
#pragma unroll
    for (int j = 0; j < 16; j++) {
        int c = cw + j;
        float y = 0.0f;
#pragma unroll
        for (int k = 0; k < 10; k++) y += xv[k] * W0f[c*10 + k];
        ht[l * HT_LD + c] = y;
    }
    __syncthreads();
    // lane = channel; walk 16 sorted points, run-combined fkey atomicMax
    unsigned int mk = 0u;
#pragma unroll
    for (int j = 0; j < 16; j++) {
        int p = cw + j;
        unsigned int k2 = fkey(ht[p * HT_LD + l]);
        mk = (k2 > mk) ? k2 : mk;
        if (j == 15 || invs[p + 1] != invs[p]) {
            atomicMax(&v0r[(long)invs[p] * 64 + l], mk);
            mk = 0u;
        }
    }
}

// ---- finalize layer-0 BN from Gram partials ----
__global__ void k_finalize0(const float* __restrict__ gramp,
                            const float* __restrict__ W0f,
                            const __hip_bfloat16* __restrict__ gamma,
                            const __hip_bfloat16* __restrict__ beta,
                            float* __restrict__ stats) {
    __shared__ float g[72];
    int t = threadIdx.x;
    if (t < 65) {
        float s = 0.0f;
        for (int slot = 0; slot < 32; slot++) s += gramp[slot * 72 + t];
        g[t] = s;
    }
    __syncthreads();
    int c = t;
    if (c >= 64) return;
    float w[10];
#pragma unroll
    for (int k = 0; k < 10; k++) w[k] = W0f[c*10 + k];
    float sum = 0.0f, sq = 0.0f;
#pragma unroll
    for (int a = 0; a < 10; a++) {
        sum += w[a] * g[a];
        float ta = 0.0f;
#pragma unroll
        for (int b = 0; b < 10; b++) {
            int hi = (a >= b) ? a : b, lo = (a >= b) ? b : a;
            ta += w[b] * g[10 + hi*(hi+1)/2 + lo];
        }
        sq += w[a] * ta;
    }
    float mu  = sum * (1.0f / NPTS);
    float var = sq * (1.0f / NPTS) - mu * mu;
    float gg  = b2f(gamma[c]) * rsqrtf(var + EPSB);
    stats[S_SC0 + c] = gg;
    stats[S_BI0 + c] = b2f(beta[c]) - mu * gg;
}

// ---- finalize layer-1 BN ----
__global__ void k_finalize1(const float* __restrict__ P1,
                            const __hip_bfloat16* __restrict__ gamma,
                            const __hip_bfloat16* __restrict__ beta,
                            float* __restrict__ stats) {
    int c = threadIdx.x;
    if (c >= 64) return;
    float sum = 0.0f, sq = 0.0f;
    for (int s = 0; s < 32; s++) {
        sum += P1[s*128 + c];
        sq  += P1[s*128 + 64 + c];
    }
    float mu  = sum * (1.0f / NPTS);
    float var = sq * (1.0f / NPTS) - mu * mu;
    float g   = b2f(gamma[c]) * rsqrtf(var + EPSB);
    stats[S_SC1 + c] = g;
    stats[S_BI1 + c] = b2f(beta[c]) - mu * g;
}

// ---- K4: layer-1 MFMA over sorted points; v0 decoded from raw keys in staging;
// run-combined raw-y1 fkey atomics (round-8 proven structure). ----
__global__ __launch_bounds__(256, 6)
void k_mfma_stats(const int* __restrict__ ord, const int* __restrict__ vsorted,
                  const __hip_bfloat16* __restrict__ feat,
                  const float* __restrict__ acc4, const int* __restrict__ coors,
                  const float* __restrict__ W0f,
                  const unsigned short* __restrict__ w1b,
                  const float* __restrict__ stats,
                  const unsigned int* __restrict__ v0r,
                  float* __restrict__ P1,
                  unsigned int* __restrict__ y1m) {
    __shared__ union {
        unsigned short xtb[64 * XTB_LD];
        float ht[64 * HT_LD];
    } sm;
    __shared__ int invs[64];
    int t = threadIdx.x, w = t >> 6, l = t & 63;
    int quad = l >> 4, lm = l & 15;
    long base = (long)blockIdx.x * 64;
    int i = ord[base + l];
    int v = vsorted[base + l];
    if (w == 0) invs[l] = v;

    bf16x8 bfrag[4];
    const uint4* wf = (const uint4*)w1b;
#pragma unroll
    for (int ks = 0; ks < 4; ks++)
        bfrag[ks] = __builtin_bit_cast(bf16x8, wf[(w * 4 + ks) * 64 + l]);

    // ---- stage x1 tile (bf16 [pt][k]) ----
    {
        int cw = w * 16;
        float xv[10];
        compute_x(feat, acc4, coors, (long)i, v, xv);
#pragma unroll
        for (int jj = 0; jj < 8; jj++) {
            int c0 = cw + 2 * jj, c1 = c0 + 1;
            float ya = 0.0f, yb = 0.0f;
#pragma unroll
            for (int k = 0; k < 10; k++) {
                ya += xv[k] * W0f[c0*10 + k];
                yb += xv[k] * W0f[c1*10 + k];
            }
            float ha = fmaxf(stats[S_SC0 + c0] * ya + stats[S_BI0 + c0], 0.0f);
            float hb = fmaxf(stats[S_SC0 + c1] * yb + stats[S_BI0 + c1], 0.0f);
            unsigned int pk = (unsigned int)bf16u(ha) | ((unsigned int)bf16u(hb) << 16);
            *(unsigned int*)&sm.xtb[l * XTB_LD + c0] = pk;
        }
    }
    {
        // v0 half: 4 lanes/pt; decode raw keys -> relu(bn0(.)) -> bf16
        int p = t >> 2, q = t & 3;
        int vv = vsorted[base + p];
        const uint4* src = (const uint4*)&v0r[(long)vv * 64 + q * 16];
#pragma unroll
        for (int u = 0; u < 4; u++) {
            uint4 kk = src[u];
            int c0 = q * 16 + u * 4;
            float h0 = fmaxf(stats[S_SC0 + c0+0] * funkey(kk.x) + stats[S_BI0 + c0+0], 0.0f);
            float h1 = fmaxf(stats[S_SC0 + c0+1] * funkey(kk.y) + stats[S_BI0 + c0+1], 0.0f);
            float h2 = fmaxf(stats[S_SC0 + c0+2] * funkey(kk.z) + stats[S_BI0 + c0+2], 0.0f);
            float h3 = fmaxf(stats[S_SC0 + c0+3] * funkey(kk.w) + stats[S_BI0 + c0+3], 0.0f);
            ushort4 s4 = { bf16u(h0), bf16u(h1), bf16u(h2), bf16u(h3) };
            *(ushort4*)&sm.xtb[p * XTB_LD + 64 + c0] = s4;
        }
    }
    __syncthreads();

    // ---- MFMA ----
    f32x4 acc[4];
#pragma unroll
    for (int pg = 0; pg < 4; pg++) acc[pg] = (f32x4){0.f, 0.f, 0.f, 0.f};
#pragma unroll
    for (int ks = 0; ks < 4; ks++) {
#pragma unroll
        for (int pg = 0; pg < 4; pg++) {
            const uint4* ap = (const uint4*)&sm.xtb[(pg * 16 + lm) * XTB_LD + ks * 32 + quad * 8];
            bf16x8 a = __builtin_bit_cast(bf16x8, *ap);
            acc[pg] = __builtin_amdgcn_mfma_f32_16x16x32_bf16(a, bfrag[ks], acc[pg], 0, 0, 0);
        }
    }

    // ---- stats from accumulators ----
    float ssum = 0.0f, ssq = 0.0f;
#pragma unroll
    for (int pg = 0; pg < 4; pg++) {
#pragma unroll
        for (int r = 0; r < 4; r++) {
            float y = acc[pg][r];
            ssum += y; ssq += y * y;
        }
    }
    __syncthreads();   // all xtb reads done -> safe to overwrite with ht

    // raw y1 -> LDS transpose (C layout: row = quad*4+r, col = lm)
#pragma unroll
    for (int pg = 0; pg < 4; pg++) {
#pragma unroll
        for (int r = 0; r < 4; r++)
            sm.ht[(pg * 16 + quad * 4 + r) * HT_LD + w * 16 + lm] = acc[pg][r];
    }
    __syncthreads();

    // lane = channel; walk 16 sorted points, combine same-voxel runs
    unsigned int mk = 0u;
    int cw = w * 16;
#pragma unroll
    for (int j = 0; j < 16; j++) {
        int p = cw + j;
        unsigned int k2 = fkey(sm.ht[p * HT_LD + l]);
        mk = (k2 > mk) ? k2 : mk;
        if (j == 15 || invs[p + 1] != invs[p]) {
            atomicMax(&y1m[(long)invs[p] * 64 + l], mk);
            mk = 0u;
        }
    }

    ssum += __shfl_xor(ssum, 16); ssq += __shfl_xor(ssq, 16);
    ssum += __shfl_xor(ssum, 32); ssq += __shfl_xor(ssq, 32);
    if (l < 16) {
        int slot = blockIdx.x & 31;
        atomicAdd(&P1[slot * 128 + w * 16 + lm], ssum);
        atomicAdd(&P1[slot * 128 + 64 + w * 16 + lm], ssq);
    }
}

// ---- K5: emit output: feats = relu(bn1(decode(y1max))), then bf16-rounded coors ----
__global__ void k_out(const unsigned int* __restrict__ y1m,
                      const float* __restrict__ stats,
                      const int* __restrict__ coors,
                      float* __restrict__ out) {
    long t = (long)blockIdx.x * 256 + threadIdx.x;
    const long nfeat = (long)NVOX * 64;
    if (t < nfeat) {
        int c = (int)(t & 63);
        float y = funkey(y1m[t]);
        out[t] = fmaxf(stats[S_SC1 + c] * y + stats[S_BI1 + c], 0.0f);
    } else if (t < nfeat + (long)NVOX * 4) {
        out[t] = b2f(__float2bfloat16((float)coors[t - nfeat]));
    }
}

extern "C" void kernel_launch(void* const* d_in, const int* in_sizes, int n_in,
                              void* d_out, int out_size, void* d_ws, size_t ws_size,
                              hipStream_t stream) {
    const __hip_bfloat16* feat = (const __hip_bfloat16*)d_in[0];
    const __hip_bfloat16* W0   = (const __hip_bfloat16*)d_in[1];
    const __hip_bfloat16* g0   = (const __hip_bfloat16*)d_in[2];
    const __hip_bfloat16* be0  = (const __hip_bfloat16*)d_in[3];
    const __hip_bfloat16* W1   = (const __hip_bfloat16*)d_in[4];
    const __hip_bfloat16* g1   = (const __hip_bfloat16*)d_in[5];
    const __hip_bfloat16* be1  = (const __hip_bfloat16*)d_in[6];
    const int* inv   = (const int*)d_in[7];
    const int* coors = (const int*)d_in[8];
    float* out = (float*)d_out;

    float* ws    = (float*)d_ws;
    float* acc4  = ws + OFF_ACC4;
    float* gramp = ws + OFF_GRAMP;
    float* stats = ws + OFF_STATS;
    float* P1    = ws + OFF_P1;
    unsigned int* v0r = (unsigned int*)(ws + OFF_V0R);
    unsigned int* y1m = (unsigned int*)(ws + OFF_Y1M);
    int* vtmp    = (int*)(ws + OFF_VTMP);
    int* bsum    = (int*)(ws + OFF_BSUM);
    int* voff    = (int*)(ws + OFF_VOFF);
    int* ord     = (int*)(ws + OFF_ORD);
    int* vsorted = (int*)(ws + OFF_VS);
    float* W0f   = ws + OFF_W0F;
    unsigned short* w1b = (unsigned short*)(ws + OFF_W1B);

    hipMemsetAsync(ws, 0, (size_t)ZERO_FLOATS * sizeof(float), stream);

    k_wconv<<<1, 256, 0, stream>>>(W0, W1, W0f, w1b);
    k_vsum<<<(4 * NPTS + 255) / 256, 256, 0, stream>>>(feat, inv, acc4);
    k_scan1<<<NBLK_SCAN, 256, 0, stream>>>(acc4, vtmp, bsum);
    k_scan2<<<1, 512, 0, stream>>>(bsum);
    k_scan3<<<NBLK_SCAN, 256, 0, stream>>>(vtmp, bsum, voff);
    k_prep<<<(NPTS + 255) / 256, 256, 0, stream>>>(inv, voff, ord, vsorted);
    k_h0gram<<<NTILE, 256, 0, stream>>>(ord, vsorted, feat, acc4, coors, W0f, gramp, v0r);
    k_finalize0<<<1, 128, 0, stream>>>(gramp, W0f, g0, be0, stats);
    k_mfma_stats<<<NTILE, 256, 0, stream>>>(ord, vsorted, feat, acc4, coors,
                                            W0f, w1b, stats, v0r, P1, y1m);
    k_finalize1<<<1, 64, 0, stream>>>(P1, g1, be1, stats);

    const long nout = (long)NVOX * 64 + (long)NVOX * 4;
    k_out<<<(int)((nout + 255) / 256), 256, 0, stream>>>(y1m, stats, coors, out);
}

// Round 11
// 292.754 us; speedup vs baseline: 1.7060x; 1.1575x over previous
//
#include <hip/hip_runtime.h>
#include <hip/hip_bf16.h>

// Problem constants (match reference)
#define NPTS 400000          // == 6250 * 64 exactly
#define NVOX 100000
#define EPSB 1e-3f
#define NTILE 6250
#define NBLK_SCAN 391        // ceil(NVOX/256)
#define GBLK 782             // k_prep grid (2-3 pts/thread)

// ws layout (in floats) — ~57 MB
#define OFF_ACC4   0                          // 4*NVOX [cnt,sx,sy,sz]
#define OFF_GRAM   (4*NVOX)                   // 72: sx[10]+sxx[55]
#define OFF_STATS  (OFF_GRAM + 72)            // 256 (sc0|bi0 used)
#define OFF_P1     (OFF_STATS + 256)          // 32 slots * 128
#define OFF_V0     (OFF_P1 + 4096)            // NVOX*64 fp32 h0 (final, plain bits)
#define OFF_Y1M    (OFF_V0 + NVOX*64)         // NVOX*64 raw y1 max (fkey)
#define ZERO_FLOATS (OFF_Y1M + NVOX*64)       // zeroed prefix (~53 MB)
#define OFF_VTMP   ZERO_FLOATS                // NVOX
#define OFF_BSUM   (OFF_VTMP + NVOX)          // 512
#define OFF_VOFF   (OFF_BSUM + 512)           // NVOX (scatter cursors)
#define OFF_VSTART (OFF_VOFF + NVOX)          // NVOX+8 (+ sentinel)
#define OFF_ORD    (OFF_VSTART + NVOX + 8)    // NPTS
#define OFF_VS     (OFF_ORD + NPTS)           // NPTS (vsorted)
#define OFF_W0F    (OFF_VS + NPTS)            // 640
#define OFF_W1B    (OFF_W0F + 640)            // 4096 floats = 8192 bf16

// stats sub-offsets
#define S_SC0 0
#define S_BI0 64

#define XTB_LD 136
#define HT_LD  65

typedef __bf16 bf16x8 __attribute__((ext_vector_type(8)));
typedef float  f32x4  __attribute__((ext_vector_type(4)));

__device__ __forceinline__ float b2f(__hip_bfloat16 h) { return __bfloat162float(h); }
__device__ __forceinline__ float bfbits2f(unsigned short u) {
    return __uint_as_float((unsigned int)u << 16);
}
__device__ __forceinline__ unsigned short bf16u(float f) {
    __hip_bfloat16 h = __float2bfloat16(f);
    return __builtin_bit_cast(unsigned short, h);
}
__device__ __forceinline__ unsigned int fkey(float f) {
    unsigned int u = __float_as_uint(f);
    return (u & 0x80000000u) ? ~u : (u | 0x80000000u);
}
__device__ __forceinline__ float funkey(unsigned int k) {
    unsigned int u = (k & 0x80000000u) ? (k & 0x7FFFFFFFu) : ~k;
    return __uint_as_float(u);
}

__device__ __forceinline__ void compute_x(const __hip_bfloat16* __restrict__ feat,
                                          const float* __restrict__ acc4,
                                          const int* __restrict__ coors,
                                          long i, int v, float* xv) {
    ushort4 f4 = *(const ushort4*)(feat + 4 * i);
    float px = bfbits2f(f4.x), py = bfbits2f(f4.y), pz = bfbits2f(f4.z), it = bfbits2f(f4.w);
    float4 a4 = *(const float4*)&acc4[4 * (long)v];
    float ic = 1.0f / a4.x;
    int4 c4 = *(const int4*)&coors[4 * (long)v];   // (b, z, y, x)
    xv[0] = px; xv[1] = py; xv[2] = pz;
    xv[3] = px - a4.y * ic; xv[4] = py - a4.z * ic; xv[5] = pz - a4.w * ic;
    xv[6] = px - ((float)c4.w * 0.2f + 0.1f);
    xv[7] = py - ((float)c4.z * 0.2f + 0.1f - 40.0f);
    xv[8] = pz - ((float)c4.y * 4.0f + 2.0f - 3.0f);
    xv[9] = it;
}

// ---- K0: W0 -> fp32; W1 -> bf16 MFMA B-fragment order ----
__global__ void k_wconv(const __hip_bfloat16* __restrict__ W0,
                        const __hip_bfloat16* __restrict__ W1,
                        float* __restrict__ W0f, unsigned short* __restrict__ w1b) {
    int t = threadIdx.x;
    for (int j = t; j < 640; j += 256) W0f[j] = b2f(W0[j]);
    for (int f = t; f < 8192; f += 256) {
        int j  = f & 7;
        int l  = (f >> 3) & 63;
        int ks = (f >> 9) & 3;
        int ct = f >> 11;
        int ch = ct * 16 + (l & 15);
        int k  = ks * 32 + ((l >> 4) & 3) * 8 + j;
        w1b[f] = __builtin_bit_cast(unsigned short, W1[ch * 128 + k]);
    }
}

// ---- K1: per-voxel count + xyz sums ----
__global__ void k_vsum(const __hip_bfloat16* __restrict__ feat,
                       const int* __restrict__ inv,
                       float* __restrict__ acc4) {
    long t = (long)blockIdx.x * 256 + threadIdx.x;
    int pt = (int)(t >> 2);
    int comp = (int)(t & 3);
    if (pt >= NPTS) return;
    float val = (comp == 0) ? 1.0f : b2f(feat[4 * pt + comp - 1]);
    int v = inv[pt];
    atomicAdd(&acc4[(long)v * 4 + comp], val);
}

// ---- prefix scan of voxel counts ----
__global__ void k_scan1(const float* __restrict__ acc4,
                        int* __restrict__ vtmp, int* __restrict__ bsum) {
    __shared__ int sc[256];
    int b = blockIdx.x, t = threadIdx.x;
    int v = b * 256 + t;
    int c = (v < NVOX) ? (int)acc4[4 * (long)v] : 0;
    sc[t] = c;
    __syncthreads();
    int val = c;
    for (int off = 1; off < 256; off <<= 1) {
        int x = (t >= off) ? sc[t - off] : 0;
        __syncthreads();
        val += x; sc[t] = val;
        __syncthreads();
    }
    if (v < NVOX) vtmp[v] = val - c;
    if (t == 255) bsum[b] = val;
}

__global__ void k_scan2(int* __restrict__ bsum) {
    __shared__ int sc[512];
    int t = threadIdx.x;
    int c = (t < NBLK_SCAN) ? bsum[t] : 0;
    sc[t] = c;
    __syncthreads();
    int val = c;
    for (int off = 1; off < 512; off <<= 1) {
        int x = (t >= off) ? sc[t - off] : 0;
        __syncthreads();
        val += x; sc[t] = val;
        __syncthreads();
    }
    if (t < NBLK_SCAN) bsum[t] = val - c;
}

__global__ void k_scan3(const int* __restrict__ vtmp, const int* __restrict__ bsum,
                        int* __restrict__ voff, int* __restrict__ vstart) {
    int v = blockIdx.x * 256 + threadIdx.x;
    if (v < NVOX) {
        int s = vtmp[v] + bsum[v >> 8];
        voff[v] = s;
        vstart[v] = s;
    }
    if (v == 0) vstart[NVOX] = NPTS;
}

// ---- K2: Gram stats (in-register, fully unrolled) + counting-sort scatter ----
__global__ __launch_bounds__(256, 4)
void k_prep(const __hip_bfloat16* __restrict__ feat,
            const int* __restrict__ inv,
            const int* __restrict__ coors,
            const float* __restrict__ acc4,
            int* __restrict__ voff,
            int* __restrict__ ord, int* __restrict__ vsorted,
            float* __restrict__ gram) {
    __shared__ float gs[72];
    int t = threadIdx.x;
    if (t < 72) gs[t] = 0.0f;
    __syncthreads();

    float sx[10], sxx[55];
#pragma unroll
    for (int a = 0; a < 10; a++) sx[a] = 0.0f;
#pragma unroll
    for (int a = 0; a < 55; a++) sxx[a] = 0.0f;

    for (long i = (long)blockIdx.x * 256 + t; i < NPTS; i += (long)GBLK * 256) {
        int v = inv[i];
        float xv[10];
        compute_x(feat, acc4, coors, i, v, xv);
        int idx = 0;
#pragma unroll
        for (int a = 0; a < 10; a++) {
            sx[a] += xv[a];
#pragma unroll
            for (int b = 0; b <= a; b++) sxx[idx++] += xv[a] * xv[b];
        }
        int pos = atomicAdd(&voff[v], 1);
        ord[pos] = (int)i;
        vsorted[pos] = v;
    }

#pragma unroll
    for (int v = 0; v < 65; v++) {
        float s = (v < 10) ? sx[v] : sxx[v - 10];
        for (int m = 32; m >= 1; m >>= 1) s += __shfl_xor(s, m);
        if ((t & 63) == 0) atomicAdd(&gs[v], s);
    }
    __syncthreads();
    if (t < 65) atomicAdd(&gram[t], gs[t]);
}

// ---- finalize layer-0 BN from Gram ----
__global__ void k_finalize0(const float* __restrict__ gram,
                            const float* __restrict__ W0f,
                            const __hip_bfloat16* __restrict__ gamma,
                            const __hip_bfloat16* __restrict__ beta,
                            float* __restrict__ stats) {
    int c = threadIdx.x;
    if (c >= 64) return;
    float w[10];
#pragma unroll
    for (int k = 0; k < 10; k++) w[k] = W0f[c*10 + k];
    float sum = 0.0f, sq = 0.0f;
#pragma unroll
    for (int a = 0; a < 10; a++) {
        sum += w[a] * gram[a];
        float ta = 0.0f;
#pragma unroll
        for (int b = 0; b < 10; b++) {
            int hi = (a >= b) ? a : b, lo = (a >= b) ? b : a;
            ta += w[b] * gram[10 + hi*(hi+1)/2 + lo];
        }
        sq += w[a] * ta;
    }
    float mu  = sum * (1.0f / NPTS);
    float var = sq * (1.0f / NPTS) - mu * mu;
    float g   = b2f(gamma[c]) * rsqrtf(var + EPSB);
    stats[S_SC0 + c] = g;
    stats[S_BI0 + c] = b2f(beta[c]) - mu * g;
}

// ---- K3: h0 = relu(bn0(y0)); sorted tile; window-complete voxels get PLAIN
// coalesced stores (no RMW), only window-spanning voxels use atomicMax. ----
__global__ __launch_bounds__(256, 6)
void k_h0max(const int* __restrict__ ord, const int* __restrict__ vsorted,
             const int* __restrict__ vstart,
             const __hip_bfloat16* __restrict__ feat,
             const float* __restrict__ acc4, const int* __restrict__ coors,
             const float* __restrict__ W0f, const float* __restrict__ stats,
             float* __restrict__ v0) {
    __shared__ float ht[64 * HT_LD];
    __shared__ int invs[64];
    int t = threadIdx.x, w = t >> 6, l = t & 63;
    int base = blockIdx.x * 64;
    int i = ord[base + l];
    int v = vsorted[base + l];
    if (w == 0) invs[l] = v;

    float xv[10];
    compute_x(feat, acc4, coors, (long)i, v, xv);
    int cw = w * 16;
#pragma unroll
    for (int j = 0; j < 16; j++) {
        int c = cw + j;
        float y = 0.0f;
#pragma unroll
        for (int k = 0; k < 10; k++) y += xv[k] * W0f[c*10 + k];
        ht[l * HT_LD + c] = fmaxf(stats[S_SC0 + c] * y + stats[S_BI0 + c], 0.0f);
    }
    __syncthreads();
    // lane = channel; wave walks its 16 sorted points; run-combine
    unsigned int mk = 0u;
#pragma unroll
    for (int j = 0; j < 16; j++) {
        int p = cw + j;
        unsigned int hb = __float_as_uint(ht[p * HT_LD + l]);
        mk = (hb > mk) ? hb : mk;
        if (j == 15 || invs[p + 1] != invs[p]) {
            int vv = invs[p];
            int s0 = vstart[vv], s1 = vstart[vv + 1];
            unsigned int* dst = (unsigned int*)&v0[(long)vv * 64 + l];
            if (s0 >= base + cw && s1 <= base + cw + 16)
                *dst = mk;                 // voxel complete in window: final value
            else
                atomicMax(dst, mk);        // spans window/tile boundary
            mk = 0u;
        }
    }
}

// ---- K4: layer-1 MFMA over sorted tiles; v0 half is a pure row copy+cvt;
// raw-y1 segment max with the same plain-store/atomic split (fkey keys). ----
__global__ __launch_bounds__(256, 6)
void k_mfma_stats(const int* __restrict__ ord, const int* __restrict__ vsorted,
                  const int* __restrict__ vstart,
                  const __hip_bfloat16* __restrict__ feat,
                  const float* __restrict__ acc4, const int* __restrict__ coors,
                  const float* __restrict__ W0f,
                  const unsigned short* __restrict__ w1b,
                  const float* __restrict__ stats,
                  const float* __restrict__ v0,
                  float* __restrict__ P1,
                  unsigned int* __restrict__ y1m) {
    __shared__ union {
        unsigned short xtb[64 * XTB_LD];
        float ht[64 * HT_LD];
    } sm;
    __shared__ int invs[64];
    int t = threadIdx.x, w = t >> 6, l = t & 63;
    int quad = l >> 4, lm = l & 15;
    int base = blockIdx.x * 64;
    int i = ord[base + l];
    int v = vsorted[base + l];
    if (w == 0) invs[l] = v;

    bf16x8 bfrag[4];
    const uint4* wf = (const uint4*)w1b;
#pragma unroll
    for (int ks = 0; ks < 4; ks++)
        bfrag[ks] = __builtin_bit_cast(bf16x8, wf[(w * 4 + ks) * 64 + l]);

    // ---- stage x1 tile (bf16 [pt][k]) ----
    {
        int cw = w * 16;
        float xv[10];
        compute_x(feat, acc4, coors, (long)i, v, xv);
#pragma unroll
        for (int jj = 0; jj < 8; jj++) {
            int c0 = cw + 2 * jj, c1 = c0 + 1;
            float ya = 0.0f, yb = 0.0f;
#pragma unroll
            for (int k = 0; k < 10; k++) {
                ya += xv[k] * W0f[c0*10 + k];
                yb += xv[k] * W0f[c1*10 + k];
            }
            float ha = fmaxf(stats[S_SC0 + c0] * ya + stats[S_BI0 + c0], 0.0f);
            float hb = fmaxf(stats[S_SC0 + c1] * yb + stats[S_BI0 + c1], 0.0f);
            unsigned int pk = (unsigned int)bf16u(ha) | ((unsigned int)bf16u(hb) << 16);
            *(unsigned int*)&sm.xtb[l * XTB_LD + c0] = pk;
        }
    }
    {
        // v0 half: 4 lanes/pt copy the voxel's final h0 row, fp32 -> bf16
        int p = t >> 2, q = t & 3;
        int vv = vsorted[base + p];
        const float4* src = (const float4*)&v0[(long)vv * 64 + q * 16];
#pragma unroll
        for (int u = 0; u < 4; u++) {
            float4 f4 = src[u];
            ushort4 s4 = { bf16u(f4.x), bf16u(f4.y), bf16u(f4.z), bf16u(f4.w) };
            *(ushort4*)&sm.xtb[p * XTB_LD + 64 + q * 16 + 4 * u] = s4;
        }
    }
    __syncthreads();

    // ---- MFMA ----
    f32x4 acc[4];
#pragma unroll
    for (int pg = 0; pg < 4; pg++) acc[pg] = (f32x4){0.f, 0.f, 0.f, 0.f};
#pragma unroll
    for (int ks = 0; ks < 4; ks++) {
#pragma unroll
        for (int pg = 0; pg < 4; pg++) {
            const uint4* ap = (const uint4*)&sm.xtb[(pg * 16 + lm) * XTB_LD + ks * 32 + quad * 8];
            bf16x8 a = __builtin_bit_cast(bf16x8, *ap);
            acc[pg] = __builtin_amdgcn_mfma_f32_16x16x32_bf16(a, bfrag[ks], acc[pg], 0, 0, 0);
        }
    }

    // ---- stats from accumulators ----
    float ssum = 0.0f, ssq = 0.0f;
#pragma unroll
    for (int pg = 0; pg < 4; pg++) {
#pragma unroll
        for (int r = 0; r < 4; r++) {
            float y = acc[pg][r];
            ssum += y; ssq += y * y;
        }
    }
    __syncthreads();   // all xtb reads done -> safe to overwrite with ht

    // raw y1 -> LDS transpose (C layout: row = quad*4+r, col = lm)
#pragma unroll
    for (int pg = 0; pg < 4; pg++) {
#pragma unroll
        for (int r = 0; r < 4; r++)
            sm.ht[(pg * 16 + quad * 4 + r) * HT_LD + w * 16 + lm] = acc[pg][r];
    }
    __syncthreads();

    // lane = channel; wave walks its 16 sorted points; plain-store/atomic split
    unsigned int mk = 0u;
    int cw = w * 16;
#pragma unroll
    for (int j = 0; j < 16; j++) {
        int p = cw + j;
        unsigned int k2 = fkey(sm.ht[p * HT_LD + l]);
        mk = (k2 > mk) ? k2 : mk;
        if (j == 15 || invs[p + 1] != invs[p]) {
            int vv = invs[p];
            int s0 = vstart[vv], s1 = vstart[vv + 1];
            unsigned int* dst = &y1m[(long)vv * 64 + l];
            if (s0 >= base + cw && s1 <= base + cw + 16)
                *dst = mk;
            else
                atomicMax(dst, mk);
            mk = 0u;
        }
    }

    ssum += __shfl_xor(ssum, 16); ssq += __shfl_xor(ssq, 16);
    ssum += __shfl_xor(ssum, 32); ssq += __shfl_xor(ssq, 32);
    if (l < 16) {
        int slot = blockIdx.x & 31;
        atomicAdd(&P1[slot * 128 + w * 16 + lm], ssum);
        atomicAdd(&P1[slot * 128 + 64 + w * 16 + lm], ssq);
    }
}

// ---- K5: emit output with INLINE BN1 finalize (per-block redundant P1 reduce).
// feats = relu(bn1(decode(y1max))); coors bf16-rounded. Grid-stride, 512 blocks.
#define OUTBLK 512
__global__ __launch_bounds__(256)
void k_out(const unsigned int* __restrict__ y1m,
           const float* __restrict__ P1,
           const __hip_bfloat16* __restrict__ gamma,
           const __hip_bfloat16* __restrict__ beta,
           const int* __restrict__ coors,
           float* __restrict__ out) {
    __shared__ float sc1s[64], bi1s[64];
    int t = threadIdx.x;
    if (t < 64) {
        float sum = 0.0f, sq = 0.0f;
        for (int s = 0; s < 32; s++) {
            sum += P1[s*128 + t];
            sq  += P1[s*128 + 64 + t];
        }
        float mu  = sum * (1.0f / NPTS);
        float var = sq * (1.0f / NPTS) - mu * mu;
        float g   = b2f(gamma[t]) * rsqrtf(var + EPSB);
        sc1s[t] = g;
        bi1s[t] = b2f(beta[t]) - mu * g;
    }
    __syncthreads();

    const long n4feat = (long)NVOX * 16;   // uint4 chunks of y1m
    const long n4all  = n4feat + NVOX;     // + int4 chunks of coors
    const long nfeat  = (long)NVOX * 64;
    for (long idx = (long)blockIdx.x * 256 + t; idx < n4all; idx += (long)OUTBLK * 256) {
        if (idx < n4feat) {
            uint4 kk = ((const uint4*)y1m)[idx];
            int c0 = (int)((idx * 4) & 63);
            float4 o;
            o.x = fmaxf(sc1s[c0+0] * funkey(kk.x) + bi1s[c0+0], 0.0f);
            o.y = fmaxf(sc1s[c0+1] * funkey(kk.y) + bi1s[c0+1], 0.0f);
            o.z = fmaxf(sc1s[c0+2] * funkey(kk.z) + bi1s[c0+2], 0.0f);
            o.w = fmaxf(sc1s[c0+3] * funkey(kk.w) + bi1s[c0+3], 0.0f);
            ((float4*)out)[idx] = o;
        } else {
            long vi = idx - n4feat;
            int4 c4 = ((const int4*)coors)[vi];
            float4 o;
            o.x = b2f(__float2bfloat16((float)c4.x));
            o.y = b2f(__float2bfloat16((float)c4.y));
            o.z = b2f(__float2bfloat16((float)c4.z));
            o.w = b2f(__float2bfloat16((float)c4.w));
            ((float4*)(out + nfeat))[vi] = o;
        }
    }
}

extern "C" void kernel_launch(void* const* d_in, const int* in_sizes, int n_in,
                              void* d_out, int out_size, void* d_ws, size_t ws_size,
                              hipStream_t stream) {
    const __hip_bfloat16* feat = (const __hip_bfloat16*)d_in[0];
    const __hip_bfloat16* W0   = (const __hip_bfloat16*)d_in[1];
    const __hip_bfloat16* g0   = (const __hip_bfloat16*)d_in[2];
    const __hip_bfloat16* be0  = (const __hip_bfloat16*)d_in[3];
    const __hip_bfloat16* W1   = (const __hip_bfloat16*)d_in[4];
    const __hip_bfloat16* g1   = (const __hip_bfloat16*)d_in[5];
    const __hip_bfloat16* be1  = (const __hip_bfloat16*)d_in[6];
    const int* inv   = (const int*)d_in[7];
    const int* coors = (const int*)d_in[8];
    float* out = (float*)d_out;

    float* ws    = (float*)d_ws;
    float* acc4  = ws + OFF_ACC4;
    float* gram  = ws + OFF_GRAM;
    float* stats = ws + OFF_STATS;
    float* P1    = ws + OFF_P1;
    float* v0    = ws + OFF_V0;
    unsigned int* y1m = (unsigned int*)(ws + OFF_Y1M);
    int* vtmp    = (int*)(ws + OFF_VTMP);
    int* bsum    = (int*)(ws + OFF_BSUM);
    int* voff    = (int*)(ws + OFF_VOFF);
    int* vstart  = (int*)(ws + OFF_VSTART);
    int* ord     = (int*)(ws + OFF_ORD);
    int* vsorted = (int*)(ws + OFF_VS);
    float* W0f   = ws + OFF_W0F;
    unsigned short* w1b = (unsigned short*)(ws + OFF_W1B);

    hipMemsetAsync(ws, 0, (size_t)ZERO_FLOATS * sizeof(float), stream);

    k_wconv<<<1, 256, 0, stream>>>(W0, W1, W0f, w1b);
    k_vsum<<<(4 * NPTS + 255) / 256, 256, 0, stream>>>(feat, inv, acc4);
    k_scan1<<<NBLK_SCAN, 256, 0, stream>>>(acc4, vtmp, bsum);
    k_scan2<<<1, 512, 0, stream>>>(bsum);
    k_scan3<<<NBLK_SCAN, 256, 0, stream>>>(vtmp, bsum, voff, vstart);
    k_prep<<<GBLK, 256, 0, stream>>>(feat, inv, coors, acc4, voff, ord, vsorted, gram);
    k_finalize0<<<1, 64, 0, stream>>>(gram, W0f, g0, be0, stats);
    k_h0max<<<NTILE, 256, 0, stream>>>(ord, vsorted, vstart, feat, acc4, coors,
                                       W0f, stats, v0);
    k_mfma_stats<<<NTILE, 256, 0, stream>>>(ord, vsorted, vstart, feat, acc4, coors,
                                            W0f, w1b, stats, v0, P1, y1m);
    k_out<<<OUTBLK, 256, 0, stream>>>(y1m, P1, g1, be1, coors, out);
}